// Round 12
// baseline (317.163 us; speedup 1.0000x reference)
//
#include <hip/hip_runtime.h>
#include <hip/hip_bf16.h>

// Problem constants
#define NC   8192
#define EC   131072
#define DC   128
#define TC   8
#define P0C  512
#define P1C  128
#define ZIC  120
#define NCAT 248          // ZIC + P1C concatenated level-1 width
#define NW0  640          // P0C + DC concatenated level-0 width
#define TEMPC 200.0f
#define ATANH_MAX 6.1053405f  // atanh(f32(1-1e-5))

typedef short short8 __attribute__((ext_vector_type(8)));
typedef float f32x4 __attribute__((ext_vector_type(4)));

__device__ inline unsigned short f2b(float f) {  // f32 -> bf16 bits, RNE
  union { float f; unsigned u; } x; x.f = f;
  unsigned r = x.u + 0x7FFFu + ((x.u >> 16) & 1u);
  return (unsigned short)(r >> 16);
}
__device__ inline float b2f(unsigned short b) {
  union { unsigned u; float f; } x; x.u = ((unsigned)b) << 16; return x.f;
}

// ---------------------------------------------------------------------------
// One-shot prep: Wcat hi/lo ([640][128] B-operand = [Ws0 | We0_pad]),
// bias0cat[640] = bs0|be0, Bcat[128][248] = [We1_pad | Ws1], biascat1[248].
// ---------------------------------------------------------------------------
__global__ void k_prep(const float* __restrict__ Ws0, const float* __restrict__ We0,
                       const float* __restrict__ bs0, const float* __restrict__ be0,
                       const float* __restrict__ We1, const float* __restrict__ Ws1,
                       const float* __restrict__ be1, const float* __restrict__ bs1,
                       unsigned short* __restrict__ WcatHi, unsigned short* __restrict__ WcatLo,
                       float* __restrict__ bias0cat,
                       float* __restrict__ Bcat, float* __restrict__ biascat1)
{
  int idx = blockIdx.x * 256 + threadIdx.x;
  const int A = NW0 * DC;          // 81920
  const int B = A + NW0;           // +640
  const int Cc = B + DC * NCAT;    // +31744
  const int Dd = Cc + NCAT;        // +248
  if (idx < A) {
    int n = idx >> 7, k = idx & 127;
    float v;
    if (n < P0C) v = Ws0[(size_t)k * P0C + n];
    else {
      int nn = n - P0C;
      v = (nn < ZIC && k >= 8) ? We0[(size_t)(k - 8) * ZIC + nn] : 0.f;
    }
    unsigned short h = f2b(v);
    WcatHi[idx] = h; WcatLo[idx] = f2b(v - b2f(h));
  } else if (idx < B) {
    int n = idx - A;
    bias0cat[n] = (n < P0C) ? bs0[n] : ((n - P0C) < ZIC ? be0[n - P0C] : 0.f);
  } else if (idx < Cc) {
    int j = idx - B;
    int k = j / NCAT, n = j - k * NCAT;
    float v;
    if (n < ZIC) v = (k >= 8) ? We1[(size_t)(k - 8) * ZIC + n] : 0.f;
    else         v = Ws1[(size_t)k * P1C + (n - ZIC)];
    Bcat[j] = v;
  } else if (idx < Dd) {
    int n = idx - Cc;
    biascat1[n] = (n < ZIC) ? be1[n] : bs1[n - ZIC];
  }
}

// ---------------------------------------------------------------------------
// hi/lo-split bf16 MFMA, K=128 fixed, fused epilogue:
//   n < 512            -> sAgg[m*512+n] (f32) + row-sumsq atomics into rs_ss[m]
//   512 <= n < 632     -> zbufT[(n-512+8)*NC + m] (bf16, transposed, ushort4)
// acc = ah@bh + ah@bl + al@bh  (al@bl ~2^-18, dropped)
// ---------------------------------------------------------------------------
__global__ __launch_bounds__(256) void k_mfma_hilo2(
    const unsigned short* __restrict__ Ahi, const unsigned short* __restrict__ Alo,
    const unsigned short* __restrict__ Bhi, const unsigned short* __restrict__ Blo,
    const float* __restrict__ bias, const float* __restrict__ degf,
    float* __restrict__ C0, unsigned short* __restrict__ zT,
    float* __restrict__ rs_ss)
{
  __shared__ unsigned short Ah[64][136], Al[64][136], Bh[64][136], Bl[64][136];
  const int bm = blockIdx.x * 64, bn = blockIdx.y * 64;
  const int tid = threadIdx.x;
  const int lane = tid & 63, wave = tid >> 6;
  const int lrow = lane & 15, lgrp = lane >> 4;
#pragma unroll
  for (int p = 0; p < 4; ++p) {
    int id = p * 256 + tid;
    int r = id >> 4, c = id & 15;
    *(uint4*)(&Ah[r][c * 8]) = *(const uint4*)(Ahi + (size_t)(bm + r) * 128 + c * 8);
    *(uint4*)(&Al[r][c * 8]) = *(const uint4*)(Alo + (size_t)(bm + r) * 128 + c * 8);
    *(uint4*)(&Bh[r][c * 8]) = *(const uint4*)(Bhi + (size_t)(bn + r) * 128 + c * 8);
    *(uint4*)(&Bl[r][c * 8]) = *(const uint4*)(Blo + (size_t)(bn + r) * 128 + c * 8);
  }
  __syncthreads();
  f32x4 acc[4];
#pragma unroll
  for (int nt = 0; nt < 4; ++nt) acc[nt] = (f32x4){0.f, 0.f, 0.f, 0.f};
#pragma unroll
  for (int kk = 0; kk < 4; ++kk) {
    short8 ah = *(const short8*)(&Ah[wave * 16 + lrow][kk * 32 + lgrp * 8]);
    short8 al = *(const short8*)(&Al[wave * 16 + lrow][kk * 32 + lgrp * 8]);
#pragma unroll
    for (int nt = 0; nt < 4; ++nt) {
      short8 bh = *(const short8*)(&Bh[nt * 16 + lrow][kk * 32 + lgrp * 8]);
      short8 bl = *(const short8*)(&Bl[nt * 16 + lrow][kk * 32 + lgrp * 8]);
      acc[nt] = __builtin_amdgcn_mfma_f32_16x16x32_bf16(ah, bh, acc[nt], 0, 0, 0);
      acc[nt] = __builtin_amdgcn_mfma_f32_16x16x32_bf16(ah, bl, acc[nt], 0, 0, 0);
      acc[nt] = __builtin_amdgcn_mfma_f32_16x16x32_bf16(al, bh, acc[nt], 0, 0, 0);
    }
  }
  if (bn < P0C) {
    // sAgg region: write f32 + accumulate row sumsq
    float pr[4] = {0.f, 0.f, 0.f, 0.f};
#pragma unroll
    for (int nt = 0; nt < 4; ++nt) {
      int n = bn + nt * 16 + lrow;
#pragma unroll
      for (int r = 0; r < 4; ++r) {
        int m = bm + wave * 16 + lgrp * 4 + r;
        float v = acc[nt][r] + degf[m] * bias[n];
        C0[(size_t)m * P0C + n] = v;
        pr[r] += v * v;
      }
    }
#pragma unroll
    for (int r = 0; r < 4; ++r) {
      float t = pr[r];
      t += __shfl_down(t, 8, 16);
      t += __shfl_down(t, 4, 16);
      t += __shfl_down(t, 2, 16);
      t += __shfl_down(t, 1, 16);
      if (lrow == 0) {
        int m = bm + wave * 16 + lgrp * 4 + r;
        atomicAdd(&rs_ss[m], t);
      }
    }
  } else {
    // z region: write bf16 transposed (4 consecutive m per lane -> ushort4)
#pragma unroll
    for (int nt = 0; nt < 4; ++nt) {
      int n = bn + nt * 16 + lrow;
      int col = n - P0C + 8;
      if (col >= DC) continue;
      int m0 = bm + wave * 16 + lgrp * 4;
      ushort4 pk;
      unsigned short* pp = (unsigned short*)&pk;
#pragma unroll
      for (int r = 0; r < 4; ++r) {
        int m = m0 + r;
        float v = acc[nt][r] + degf[m] * bias[n];
        pp[r] = f2b(v);
      }
      *(ushort4*)(zT + (size_t)col * NC + m0) = pk;
    }
  }
}

// rs[r] = TEMP * min(||row||, ATANH_MAX) / ||row|| from accumulated sumsq
__global__ void k_rs_final(const float* __restrict__ rs_ss, float* __restrict__ rs)
{
  int r = blockIdx.x * 256 + threadIdx.x;
  if (r >= NC) return;
  float n = sqrtf(rs_ss[r]);
  n = fmaxf(n, 1e-15f);
  rs[r] = TEMPC * fminf(n, ATANH_MAX) / n;
}

// ---------------------------------------------------------------------------
// f32 NN GEMM, split-K partials (level-1)
// ---------------------------------------------------------------------------
__global__ __launch_bounds__(256) void k_gemm_nn_part(
    const float* __restrict__ A, int lda,
    const float* __restrict__ B, int ldb,
    float* __restrict__ part,
    int M, int N, int K, int kchunk)
{
  __shared__ float As[16][65];
  __shared__ float Bs[16][65];
  int bm = blockIdx.x * 64, bn = blockIdx.y * 64;
  int z = blockIdx.z;
  int ks = z * kchunk, ke = min(K, ks + kchunk);
  int tid = threadIdx.x;
  int tm = (tid >> 4) << 2, tn = (tid & 15) << 2;
  float acc[4][4] = {};
  for (int k0 = ks; k0 < ke; k0 += 16) {
    for (int i = tid; i < 1024; i += 256) {
      int m = i >> 4, k = i & 15;
      float v = 0.f;
      if (bm + m < M && k0 + k < ke) v = A[(size_t)(bm + m) * lda + k0 + k];
      As[k][m] = v;
    }
    for (int i = tid; i < 1024; i += 256) {
      int k = i >> 6, n = i & 63;
      float v = 0.f;
      if (k0 + k < ke && bn + n < N) v = B[(size_t)(k0 + k) * ldb + bn + n];
      Bs[k][n] = v;
    }
    __syncthreads();
#pragma unroll
    for (int kk = 0; kk < 16; ++kk) {
      float a[4], b[4];
#pragma unroll
      for (int i = 0; i < 4; i++) a[i] = As[kk][tm + i];
#pragma unroll
      for (int j = 0; j < 4; j++) b[j] = Bs[kk][tn + j];
#pragma unroll
      for (int i = 0; i < 4; i++)
#pragma unroll
        for (int j = 0; j < 4; j++) acc[i][j] += a[i] * b[j];
    }
    __syncthreads();
  }
  size_t base = (size_t)z * M * N;
#pragma unroll
  for (int i = 0; i < 4; i++) {
    int m = bm + tm + i; if (m >= M) continue;
#pragma unroll
    for (int j = 0; j < 4; j++) {
      int n = bn + tn + j; if (n >= N) continue;
      part[base + (size_t)m * N + n] = acc[i][j];
    }
  }
}

__global__ void k_reduce_bias(const float* __restrict__ part,
                              const float* __restrict__ bias,
                              float* __restrict__ C, int nparts, int M, int N)
{
  int idx = blockIdx.x * 256 + threadIdx.x;
  if (idx >= M * N) return;
  int n = idx % N;
  float s = 0.f;
  for (int p = 0; p < nparts; ++p) s += part[(size_t)p * M * N + idx];
  if (bias) s += bias[n];
  C[idx] = s;
}

// stage-B reduce: split 512x248 partials into z1[:,8:128] and s1agg; tail copies z1[:, :8]
__global__ void k_reduce_stageB(const float* __restrict__ part,
                                const float* __restrict__ x1f,
                                float* __restrict__ z1, float* __restrict__ s1agg,
                                int nparts)
{
  int idx = blockIdx.x * 256 + threadIdx.x;
  const int MN = P0C * NCAT;
  if (idx < MN) {
    int m = idx / NCAT, n = idx - m * NCAT;
    float s = 0.f;
    for (int p = 0; p < nparts; ++p) s += part[(size_t)p * MN + idx];
    if (n < ZIC) z1[(size_t)m * DC + 8 + n] = s;
    else         s1agg[(size_t)m * P1C + (n - ZIC)] = s;
  } else if (idx < MN + P0C * 8) {
    int r = idx - MN; int m = r >> 3, c = r & 7;
    z1[(size_t)m * DC + c] = x1f[(size_t)m * DC + c];
  }
}

// ---------------------------------------------------------------------------
// Small f32 TN GEMM with split-K + atomics (x2 product)
// ---------------------------------------------------------------------------
__global__ __launch_bounds__(256) void k_gemm_tn(
    const float* __restrict__ A, int lda,
    const float* __restrict__ B, int ldb,
    float* __restrict__ C, int ldc,
    int M, int N, int K, int kchunk)
{
  __shared__ float As[16][65];
  __shared__ float Bs[16][65];
  int bm = blockIdx.x * 64, bn = blockIdx.y * 64;
  int ks = blockIdx.z * kchunk;
  int ke = min(K, ks + kchunk);
  int tid = threadIdx.x;
  int tm = (tid >> 4) << 2, tn = (tid & 15) << 2;
  float acc[4][4] = {};
  for (int k0 = ks; k0 < ke; k0 += 16) {
    for (int i = tid; i < 1024; i += 256) {
      int k = i >> 6, m = i & 63;
      float v = 0.f;
      if (k0 + k < ke && bm + m < M) v = A[(size_t)(k0 + k) * lda + bm + m];
      As[k][m] = v;
    }
    for (int i = tid; i < 1024; i += 256) {
      int k = i >> 6, n = i & 63;
      float v = 0.f;
      if (k0 + k < ke && bn + n < N) v = B[(size_t)(k0 + k) * ldb + bn + n];
      Bs[k][n] = v;
    }
    __syncthreads();
#pragma unroll
    for (int kk = 0; kk < 16; ++kk) {
      float a[4], b[4];
#pragma unroll
      for (int i = 0; i < 4; i++) a[i] = As[kk][tm + i];
#pragma unroll
      for (int j = 0; j < 4; j++) b[j] = Bs[kk][tn + j];
#pragma unroll
      for (int i = 0; i < 4; i++)
#pragma unroll
        for (int j = 0; j < 4; j++) acc[i][j] += a[i] * b[j];
    }
    __syncthreads();
  }
#pragma unroll
  for (int i = 0; i < 4; i++) {
    int m = bm + tm + i; if (m >= M) continue;
#pragma unroll
    for (int j = 0; j < 4; j++) {
      int n = bn + tn + j; if (n >= N) continue;
      atomicAdd(&C[(size_t)m * ldc + n], acc[i][j]);
    }
  }
}

// bf16 -> bf16 64x64 tile transpose
__global__ __launch_bounds__(256) void k_transpose_b2b(
    const unsigned short* __restrict__ src, int R, int C,
    unsigned short* __restrict__ dst)
{
  __shared__ unsigned short tile[64][65];
  int br = blockIdx.x * 64, bc = blockIdx.y * 64;
  for (int idx = threadIdx.x; idx < 4096; idx += 256) {
    int r = idx >> 6, c = idx & 63;
    tile[r][c] = src[(size_t)(br + r) * C + bc + c];
  }
  __syncthreads();
  for (int idx = threadIdx.x; idx < 4096; idx += 256) {
    int c = idx >> 6, r = idx & 63;
    dst[(size_t)(bc + c) * R + br + r] = tile[r][c];
  }
}

// ---------------------------------------------------------------------------
// bf16 MFMA NT GEMM: Cpart[z][M][N] = sum_k At[m][k]*Bt[n][k] over k-chunk z.
// ---------------------------------------------------------------------------
__global__ __launch_bounds__(256) void k_nt_bf16(
    const unsigned short* __restrict__ At,
    const unsigned short* __restrict__ Bt,
    float* __restrict__ Cpart,
    int M, int N, int K, int kchunk)
{
  __shared__ unsigned short Alds[64][136];
  __shared__ unsigned short Blds[64][136];
  const int bm = blockIdx.x * 64, bn = blockIdx.y * 64;
  const int z = blockIdx.z;
  const int k_beg = z * kchunk, k_end = k_beg + kchunk;
  const int tid = threadIdx.x;
  const int lane = tid & 63, wave = tid >> 6;
  const int lrow = lane & 15, lgrp = lane >> 4;
  f32x4 acc[4];
#pragma unroll
  for (int nt = 0; nt < 4; ++nt) acc[nt] = (f32x4){0.f, 0.f, 0.f, 0.f};

  for (int k0 = k_beg; k0 < k_end; k0 += 128) {
#pragma unroll
    for (int p = 0; p < 4; ++p) {
      int id = p * 256 + tid;
      int r = id >> 4;
      int c = id & 15;
      *(uint4*)(&Alds[r][c * 8]) =
          *(const uint4*)(At + (size_t)(bm + r) * K + k0 + c * 8);
      *(uint4*)(&Blds[r][c * 8]) =
          *(const uint4*)(Bt + (size_t)(bn + r) * K + k0 + c * 8);
    }
    __syncthreads();
#pragma unroll
    for (int kk = 0; kk < 4; ++kk) {
      short8 af = *(const short8*)(&Alds[wave * 16 + lrow][kk * 32 + lgrp * 8]);
#pragma unroll
      for (int nt = 0; nt < 4; ++nt) {
        short8 bf = *(const short8*)(&Blds[nt * 16 + lrow][kk * 32 + lgrp * 8]);
        acc[nt] = __builtin_amdgcn_mfma_f32_16x16x32_bf16(af, bf, acc[nt], 0, 0, 0);
      }
    }
    __syncthreads();
  }
  size_t base = (size_t)z * M * N;
#pragma unroll
  for (int nt = 0; nt < 4; ++nt) {
    int n = bn + nt * 16 + lrow;
#pragma unroll
    for (int r = 0; r < 4; ++r) {
      int m = bm + wave * 16 + lgrp * 4 + r;
      Cpart[base + (size_t)m * N + n] = acc[nt][r];
    }
  }
}

__global__ void k_reduce_parts(const float* __restrict__ part, float* __restrict__ C,
                               int nparts, int sz)
{
  int idx = blockIdx.x * 256 + threadIdx.x;
  if (idx >= sz) return;
  float s = 0.f;
  for (int p = 0; p < nparts; ++p) s += part[(size_t)p * sz + idx];
  C[idx] = s;
}

// ---------------------------------------------------------------------------
// CSR build (+degf folded into scan)
// ---------------------------------------------------------------------------
__global__ void k_count(const int* __restrict__ adj, int* __restrict__ counts)
{
  int e = blockIdx.x * 256 + threadIdx.x;
  if (e < EC) atomicAdd(&counts[adj[e]], 1);
}

__global__ __launch_bounds__(1024) void k_scan(const int* __restrict__ counts,
                                               int* __restrict__ offsets,
                                               float* __restrict__ degf)
{
  __shared__ int tsum[1024];
  int tid = threadIdx.x;
  int base = tid * 8;
  int loc[8]; int s = 0;
#pragma unroll
  for (int i = 0; i < 8; i++) { loc[i] = s; s += counts[base + i]; }
  tsum[tid] = s;
  __syncthreads();
  for (int off = 1; off < 1024; off <<= 1) {
    int v = (tid >= off) ? tsum[tid - off] : 0;
    __syncthreads();
    tsum[tid] += v;
    __syncthreads();
  }
  int excl = (tid == 0) ? 0 : tsum[tid - 1];
#pragma unroll
  for (int i = 0; i < 8; i++) {
    offsets[base + i] = excl + loc[i];
    degf[base + i] = (float)counts[base + i];
  }
  if (tid == 1023) offsets[NC] = tsum[1023];
}

__global__ void k_scatter(const int* __restrict__ adj, const int* __restrict__ offsets,
                          int* __restrict__ fill, int* __restrict__ csr)
{
  int e = blockIdx.x * 256 + threadIdx.x;
  if (e < EC) {
    int d = adj[e], s = adj[EC + e];
    int p = atomicAdd(&fill[d], 1);
    csr[offsets[d] + p] = s;
  }
}

// ---------------------------------------------------------------------------
// Aggregate raw x rows (multiplicity) -> hi/lo bf16 split of xa; also writes
// the 8 leading x-columns transposed into zbufT (bf16).
// ---------------------------------------------------------------------------
__global__ __launch_bounds__(128) void k_aggX(
    const int* __restrict__ offsets, const int* __restrict__ csr,
    const float* __restrict__ x,
    unsigned short* __restrict__ hi, unsigned short* __restrict__ lo,
    unsigned short* __restrict__ zT)
{
  int j = blockIdx.x;
  int beg = offsets[j], deg = offsets[j + 1] - beg;
  __shared__ int srcs[512];
  bool inl = (deg <= 512);
  if (inl) for (int i = threadIdx.x; i < deg; i += 128) srcs[i] = csr[beg + i];
  __syncthreads();
  int c = threadIdx.x;
  float acc = 0.f;
  if (inl) {
    int i = 0;
    for (; i + 4 <= deg; i += 4) {
      int s0 = srcs[i], s1 = srcs[i+1], s2 = srcs[i+2], s3 = srcs[i+3];
      float v0 = x[(size_t)s0 * DC + c], v1 = x[(size_t)s1 * DC + c];
      float v2 = x[(size_t)s2 * DC + c], v3 = x[(size_t)s3 * DC + c];
      acc += v0; acc += v1; acc += v2; acc += v3;
    }
    for (; i < deg; ++i) acc += x[(size_t)srcs[i] * DC + c];
  } else {
    for (int i = 0; i < deg; ++i) acc += x[(size_t)csr[beg + i] * DC + c];
  }
  unsigned short h = f2b(acc);
  hi[(size_t)j * DC + c] = h;
  lo[(size_t)j * DC + c] = f2b(acc - b2f(h));
  if (c < 8) zT[(size_t)c * NC + j] = f2b(x[(size_t)j * DC + c]);
}

// ---------------------------------------------------------------------------
// Mbh = bf16(A0_dedup @ S0): 512 threads, 1 col each; x8 ILP gather.
// ---------------------------------------------------------------------------
__global__ __launch_bounds__(512) void k_aggM_bf16(
    const int* __restrict__ offsets, const int* __restrict__ csr,
    const unsigned short* __restrict__ S0h, unsigned short* __restrict__ Mbh)
{
  int j = blockIdx.x;
  int beg = offsets[j], deg = offsets[j + 1] - beg;
  __shared__ int srcs[512];
  __shared__ int nv_s;
  bool inl = (deg <= 512);
  if (inl) for (int i = threadIdx.x; i < deg; i += 512) srcs[i] = csr[beg + i];
  __syncthreads();
  if (inl) {
    for (int t = threadIdx.x; t < deg; t += 512) {
      int v = srcs[t];
      for (int u = 0; u < t; ++u)
        if (csr[beg + u] == v) { srcs[t] = -1; break; }
    }
  }
  __syncthreads();
  if (threadIdx.x == 0) {
    int nv = 0;
    if (inl) {
      for (int i = 0; i < deg; i++) if (srcs[i] >= 0) srcs[nv++] = srcs[i];
    }
    nv_s = nv;
  }
  __syncthreads();
  int c = threadIdx.x;
  float a0 = 0.f;
  if (inl) {
    int nv = nv_s;
    int i = 0;
    for (; i + 8 <= nv; i += 8) {
      float v0 = b2f(S0h[(size_t)srcs[i]   * P0C + c]);
      float v1 = b2f(S0h[(size_t)srcs[i+1] * P0C + c]);
      float v2 = b2f(S0h[(size_t)srcs[i+2] * P0C + c]);
      float v3 = b2f(S0h[(size_t)srcs[i+3] * P0C + c]);
      float v4 = b2f(S0h[(size_t)srcs[i+4] * P0C + c]);
      float v5 = b2f(S0h[(size_t)srcs[i+5] * P0C + c]);
      float v6 = b2f(S0h[(size_t)srcs[i+6] * P0C + c]);
      float v7 = b2f(S0h[(size_t)srcs[i+7] * P0C + c]);
      a0 += v0 + v1 + v2 + v3 + v4 + v5 + v6 + v7;
    }
    for (; i < nv; ++i) a0 += b2f(S0h[(size_t)srcs[i] * P0C + c]);
  } else {
    for (int i = 0; i < deg; i++) {
      int s = csr[beg + i];
      bool dup = false;
      for (int u = 0; u < i; u++) if (csr[beg + u] == s) { dup = true; break; }
      if (!dup) a0 += b2f(S0h[(size_t)s * P0C + c]);
    }
  }
  Mbh[(size_t)j * P0C + c] = f2b(a0);
}

// ---------------------------------------------------------------------------
// Column softmax (axis=0) over 8192 rows, two-stage online
// ---------------------------------------------------------------------------
__global__ __launch_bounds__(256) void k_smaxA(const float* __restrict__ U,
    const float* __restrict__ rs, float* __restrict__ pm, float* __restrict__ ps,
    int rows, int cols, int rpg)
{
  int lc = threadIdx.x & 63;
  int c = blockIdx.x * 64 + lc;
  int rl = threadIdx.x >> 6;
  int r0 = blockIdx.y * rpg, r1 = min(rows, r0 + rpg);
  float m = -1e30f, s = 0.f;
  for (int r = r0 + rl; r < r1; r += 4) {
    float l = rs[r] * U[(size_t)r * cols + c];
    if (l > m) { s = s * __expf(m - l) + 1.f; m = l; }
    else s += __expf(l - m);
  }
  __shared__ float sm[4][64], sv[4][64];
  sm[rl][lc] = m; sv[rl][lc] = s;
  __syncthreads();
  if (threadIdx.x < 64) {
    float mm = sm[0][threadIdx.x], s2 = sv[0][threadIdx.x];
    for (int q = 1; q < 4; q++) {
      float mq = sm[q][threadIdx.x], sq = sv[q][threadIdx.x];
      float mn = fmaxf(mm, mq);
      s2 = s2 * __expf(mm - mn) + sq * __expf(mq - mn);
      mm = mn;
    }
    pm[(size_t)blockIdx.y * cols + blockIdx.x * 64 + threadIdx.x] = mm;
    ps[(size_t)blockIdx.y * cols + blockIdx.x * 64 + threadIdx.x] = s2;
  }
}

__global__ void k_smaxB(const float* __restrict__ pm, const float* __restrict__ ps,
                        float* __restrict__ colm, float* __restrict__ colsum,
                        int ng, int cols)
{
  int c = blockIdx.x * blockDim.x + threadIdx.x;
  if (c >= cols) return;
  float m = -1e30f, s = 0.f;
  for (int g = 0; g < ng; g++) {
    float mg = pm[(size_t)g * cols + c], sg = ps[(size_t)g * cols + c];
    float mn = fmaxf(m, mg);
    s = s * __expf(m - mn) + sg * __expf(mg - mn);
    m = mn;
  }
  colm[c] = m; colsum[c] = s;
}

// Final softmax pass: writes row-major bf16 Sh AND transposed bf16 ST, + entropy.
__global__ __launch_bounds__(256) void k_smaxC(const float* __restrict__ U,
    const float* __restrict__ rs, const float* __restrict__ colm,
    const float* __restrict__ colsum,
    unsigned short* __restrict__ Sh, unsigned short* __restrict__ ST,
    float* __restrict__ loss, int rows, int cols)
{
  __shared__ unsigned short tile[64][258];
  __shared__ float red[4];
  int lc = threadIdx.x & 63;
  int gc = blockIdx.x * 64 + lc;
  int rl = threadIdx.x >> 6;
  int r0 = blockIdx.y * 256;
  float m = colm[gc], inv = 1.f / colsum[gc];
  float h = 0.f;
  for (int rr = rl; rr < 256; rr += 4) {
    int r = r0 + rr;
    float l = rs[r] * U[(size_t)r * cols + gc];
    float p = __expf(l - m) * inv;
    unsigned short pb = f2b(p);
    Sh[(size_t)r * cols + gc] = pb;
    tile[lc][rr] = pb;
    if (p > 0.f) h -= p * __logf(p);
  }
  for (int off = 32; off > 0; off >>= 1) h += __shfl_down(h, off);
  if ((threadIdx.x & 63) == 0) red[threadIdx.x >> 6] = h;
  __syncthreads();
  if (threadIdx.x == 0) atomicAdd(loss, red[0] + red[1] + red[2] + red[3]);
  int gc0 = blockIdx.x * 64;
  for (int idx = threadIdx.x; idx < 64 * 256; idx += 256) {
    int col = idx >> 8, rr = idx & 255;
    ST[(size_t)(gc0 + col) * rows + r0 + rr] = tile[col][rr];
  }
}

// ---------------------------------------------------------------------------
// Level-1: row scale (small) + column softmax
// ---------------------------------------------------------------------------
__global__ __launch_bounds__(256) void k_rowscale(const float* __restrict__ U, int cols,
                                                  float* __restrict__ rs)
{
  int r = blockIdx.x;
  const float* row = U + (size_t)r * cols;
  float ss = 0.f;
  for (int c = threadIdx.x; c < cols; c += 256) { float v = row[c]; ss += v * v; }
  for (int off = 32; off > 0; off >>= 1) ss += __shfl_down(ss, off);
  __shared__ float red[4];
  if ((threadIdx.x & 63) == 0) red[threadIdx.x >> 6] = ss;
  __syncthreads();
  if (threadIdx.x == 0) {
    float n = sqrtf(red[0] + red[1] + red[2] + red[3]);
    n = fmaxf(n, 1e-15f);
    rs[r] = TEMPC * fminf(n, ATANH_MAX) / n;
  }
}

__global__ __launch_bounds__(256) void k_smax_col(const float* __restrict__ U,
    const float* __restrict__ rs, float* __restrict__ S, float* __restrict__ loss,
    int rows, int cols)
{
  int c = blockIdx.x;
  int tid = threadIdx.x;
  int r0 = tid, r1 = tid + 256;
  float v0 = rs[r0] * U[(size_t)r0 * cols + c];
  float v1 = rs[r1] * U[(size_t)r1 * cols + c];
  float m = fmaxf(v0, v1);
  for (int off = 32; off > 0; off >>= 1) m = fmaxf(m, __shfl_xor(m, off));
  __shared__ float red[4];
  if ((tid & 63) == 0) red[tid >> 6] = m;
  __syncthreads();
  m = fmaxf(fmaxf(red[0], red[1]), fmaxf(red[2], red[3]));
  float e0 = __expf(v0 - m), e1 = __expf(v1 - m);
  float s = e0 + e1;
  for (int off = 32; off > 0; off >>= 1) s += __shfl_xor(s, off);
  __syncthreads();
  __shared__ float red2[4];
  if ((tid & 63) == 0) red2[tid >> 6] = s;
  __syncthreads();
  s = red2[0] + red2[1] + red2[2] + red2[3];
  float inv = 1.f / s;
  float p0 = e0 * inv, p1 = e1 * inv;
  S[(size_t)r0 * cols + c] = p0;
  S[(size_t)r1 * cols + c] = p1;
  float h = 0.f;
  if (p0 > 0.f) h -= p0 * __logf(p0);
  if (p1 > 0.f) h -= p1 * __logf(p1);
  for (int off = 32; off > 0; off >>= 1) h += __shfl_xor(h, off);
  __syncthreads();
  __shared__ float red3[4];
  if ((tid & 63) == 0) red3[tid >> 6] = h;
  __syncthreads();
  if (tid == 0) atomicAdd(loss, red3[0] + red3[1] + red3[2] + red3[3]);
}

// ---------------------------------------------------------------------------
// y-projection via split-K partials (f32 S variant and bf16 S variant)
// ---------------------------------------------------------------------------
__global__ __launch_bounds__(256) void k_yS_part(
    const float* __restrict__ Y, int ldy,
    const float* __restrict__ S, int ldS,
    float* __restrict__ part, int K, int C, int kchunk)
{
  int lc = threadIdx.x & 63;
  int c = blockIdx.x * 64 + lc;
  int rl = threadIdx.x >> 6;
  int r0 = blockIdx.y * kchunk, r1 = min(K, r0 + kchunk);
  float acc[8] = {};
  for (int r = r0 + rl; r < r1; r += 4) {
    float sv = S[(size_t)r * ldS + c];
#pragma unroll
    for (int t = 0; t < 8; t++) acc[t] += Y[(size_t)t * ldy + r] * sv;
  }
  __shared__ float red[4][8][64];
#pragma unroll
  for (int t = 0; t < 8; t++) red[rl][t][lc] = acc[t];
  __syncthreads();
  if (rl == 0) {
#pragma unroll
    for (int t = 0; t < 8; t++) {
      float v = red[0][t][lc] + red[1][t][lc] + red[2][t][lc] + red[3][t][lc];
      part[((size_t)blockIdx.y * 8 + t) * C + c] = v;
    }
  }
}

__global__ __launch_bounds__(256) void k_yS_part_b(
    const float* __restrict__ Y, int ldy,
    const unsigned short* __restrict__ S, int ldS,
    float* __restrict__ part, int K, int C, int kchunk)
{
  int lc = threadIdx.x & 63;
  int c = blockIdx.x * 64 + lc;
  int rl = threadIdx.x >> 6;
  int r0 = blockIdx.y * kchunk, r1 = min(K, r0 + kchunk);
  float acc[8] = {};
  for (int r = r0 + rl; r < r1; r += 4) {
    float sv = b2f(S[(size_t)r * ldS + c]);
#pragma unroll
    for (int t = 0; t < 8; t++) acc[t] += Y[(size_t)t * ldy + r] * sv;
  }
  __shared__ float red[4][8][64];
#pragma unroll
  for (int t = 0; t < 8; t++) red[rl][t][lc] = acc[t];
  __syncthreads();
  if (rl == 0) {
#pragma unroll
    for (int t = 0; t < 8; t++) {
      float v = red[0][t][lc] + red[1][t][lc] + red[2][t][lc] + red[3][t][lc];
      part[((size_t)blockIdx.y * 8 + t) * C + c] = v;
    }
  }
}

__global__ void k_yS_red(const float* __restrict__ part, float* __restrict__ outp,
                         int nparts, int sz)
{
  int idx = blockIdx.x * 256 + threadIdx.x;
  if (idx >= sz) return;
  float s = 0.f;
  for (int p = 0; p < nparts; ++p) s += part[(size_t)p * sz + idx];
  outp[idx] = s;
}

// ---------------------------------------------------------------------------
// Single fused output emit (all regions of d_out)
// ---------------------------------------------------------------------------
__global__ void k_emit_all(const float* __restrict__ x, const float* __restrict__ x1f,
                           const float* __restrict__ x2f, const float* __restrict__ y,
                           const float* __restrict__ y1f, const float* __restrict__ y2f,
                           const float* __restrict__ lossf, float* __restrict__ out,
                           int total)
{
  int idx = blockIdx.x * 256 + threadIdx.x;
  if (idx >= total) return;
  float v;
  if (idx < 1048576) v = x[idx];                       // NC*DC
  else if (idx < 1114112) v = x1f[idx - 1048576];      // +P0C*DC
  else if (idx < 1130496) v = x2f[idx - 1114112];      // +P1C*DC
  else if (idx < 1201152) {                            // y region, YW=8832
    int r = idx - 1130496;
    int t = r / 8832, c = r - t * 8832;
    if (c < 8192) v = y[(size_t)t * 8192 + c];
    else if (c < 8704) v = y1f[t * 512 + (c - 8192)];
    else v = y2f[t * 128 + (c - 8704)];
  } else v = lossf[0];
  out[idx] = v;
}

// ---------------------------------------------------------------------------
extern "C" void kernel_launch(void* const* d_in, const int* in_sizes, int n_in,
                              void* d_out, int out_size, void* d_ws, size_t ws_size,
                              hipStream_t stream)
{
  (void)in_sizes; (void)n_in; (void)ws_size;
  const float* x   = (const float*)d_in[0];
  const float* y   = (const float*)d_in[1];
  const float* We0 = (const float*)d_in[2];
  const float* be0 = (const float*)d_in[3];
  const float* Ws0 = (const float*)d_in[4];
  const float* bs0 = (const float*)d_in[5];
  const float* We1 = (const float*)d_in[6];
  const float* be1 = (const float*)d_in[7];
  const float* Ws1 = (const float*)d_in[8];
  const float* bs1 = (const float*)d_in[9];
  const int*   adj = (const int*)d_in[10];
  float* out = (float*)d_out;

  float* ws = (float*)d_ws;
  size_t o = 0;
  auto alloc = [&](size_t n) { float* p = ws + o; o += n; return p; };
  float* sAgg  = alloc((size_t)NC * P0C);    // logits; then Mbh(bf16) + A1 partials
  float* zbuf  = alloc((size_t)NC * DC);     // x1 partials only
  float* rsc   = alloc(NC);
  float* degf  = alloc(NC);
  float* pm    = alloc(32 * P0C);
  float* ps    = alloc(32 * P0C);
  float* colm  = alloc(P0C);
  float* colsum= alloc(P0C);
  float* s1agg = alloc((size_t)P0C * P1C);
  float* S1    = alloc((size_t)P0C * P1C);
  float* z1    = alloc((size_t)P0C * P1C);
  float* rs1   = alloc(P0C);
  float* x1f   = alloc((size_t)P0C * DC);
  float* A1    = alloc((size_t)P0C * P0C);
  unsigned short* S0T   = (unsigned short*)alloc((size_t)P0C * NC / 2);
  unsigned short* MbT   = (unsigned short*)alloc((size_t)P0C * NC / 2);
  unsigned short* zbufT = (unsigned short*)alloc((size_t)DC * NC / 2);
  unsigned short* S0h   = (unsigned short*)alloc((size_t)NC * P0C / 2);
  unsigned short* xaHi  = (unsigned short*)alloc((size_t)NC * DC / 2);
  unsigned short* xaLo  = (unsigned short*)alloc((size_t)NC * DC / 2);
  unsigned short* WcatHi= (unsigned short*)alloc((size_t)NW0 * DC / 2);
  unsigned short* WcatLo= (unsigned short*)alloc((size_t)NW0 * DC / 2);
  float* bias0cat = alloc(NW0);
  float* Bcat   = alloc((size_t)DC * NCAT);
  float* biascat1= alloc(NCAT);
  float* t1s1   = alloc((size_t)P0C * NCAT);
  float* partSA = alloc((size_t)4 * P0C * NCAT);
  float* partSB = alloc((size_t)8 * P0C * NCAT);
  float* partY1 = alloc((size_t)128 * TC * P0C);
  float* partY2 = alloc((size_t)8 * TC * P1C);
  // atomic-accumulated zone (contiguous, zeroed every call)
  float* rs_ss = alloc(NC);
  float* x2f   = alloc((size_t)P1C * DC);
  float* y1f   = alloc((size_t)TC * P0C);
  float* y2f   = alloc((size_t)TC * P1C);
  float* lossf = alloc(1);
  size_t atomicFloats = (size_t)NC + (size_t)P1C*DC + (size_t)TC*P0C + (size_t)TC*P1C + 1;
  o = (o + 63) & ~(size_t)63;
  int* ibase   = (int*)(ws + o);
  int* counts  = ibase;
  int* fill    = ibase + NC;
  int* offsets = ibase + 2 * NC;
  int* csr     = ibase + 2 * NC + (NC + 1);

  unsigned short* Mbh = (unsigned short*)sAgg;          // bf16 8192x512 (8 MB)
  float* partsA1 = sAgg + (size_t)2 * 1024 * 1024;      // 8x512x512 f32 (8 MB)
  float* partsX1 = zbuf;                                // 16x512x128 f32

  hipMemsetAsync(rs_ss, 0, atomicFloats * sizeof(float), stream);
  hipMemsetAsync(counts, 0, 2 * NC * sizeof(int), stream);

  // ---- CSR build + degree + weight preps ----
  k_count  <<<EC/256, 256, 0, stream>>>(adj, counts);
  k_scan   <<<1, 1024, 0, stream>>>(counts, offsets, degf);
  k_scatter<<<EC/256, 256, 0, stream>>>(adj, offsets, fill, csr);
  k_prep<<<(NW0*DC + NW0 + DC*NCAT + NCAT + 255)/256, 256, 0, stream>>>(
      Ws0, We0, bs0, be0, We1, Ws1, be1, bs1,
      WcatHi, WcatLo, bias0cat, Bcat, biascat1);

  // ---- aggregate raw x (hi/lo direct), fused MFMA: sAgg + zbufT + rs_ss ----
  k_aggX<<<NC, 128, 0, stream>>>(offsets, csr, x, xaHi, xaLo, zbufT);
  k_mfma_hilo2<<<dim3(NC/64, NW0/64), 256, 0, stream>>>(xaHi, xaLo, WcatHi, WcatLo,
                                                        bias0cat, degf, sAgg, zbufT, rs_ss);
  k_rs_final<<<NC/256, 256, 0, stream>>>(rs_ss, rsc);

  // ---- column softmax -> S0h + S0T, entropy ----
  k_smaxA<<<dim3(P0C/64, 32), 256, 0, stream>>>(sAgg, rsc, pm, ps, NC, P0C, 256);
  k_smaxB<<<P0C/256, 256, 0, stream>>>(pm, ps, colm, colsum, 32, P0C);
  k_smaxC<<<dim3(P0C/64, 32), 256, 0, stream>>>(sAgg, rsc, colm, colsum, S0h, S0T, lossf, NC, P0C);

  // ---- Mbh = bf16(A0_dedup @ S0) ; transpose ----
  k_aggM_bf16<<<NC, 512, 0, stream>>>(offsets, csr, S0h, Mbh);
  k_transpose_b2b<<<dim3(NC/64, P0C/64), 256, 0, stream>>>(Mbh, NC, P0C, MbT);

  // ---- pooled products via bf16 MFMA (split-K partials + reduce) ----
  k_nt_bf16<<<dim3(P0C/64, P0C/64, 8), 256, 0, stream>>>(S0T, MbT, partsA1, P0C, P0C, NC, 1024);
  k_reduce_parts<<<(P0C*P0C)/256, 256, 0, stream>>>(partsA1, A1, 8, P0C*P0C);
  k_nt_bf16<<<dim3(P0C/64, DC/64, 16), 256, 0, stream>>>(S0T, zbufT, partsX1, P0C, DC, NC, 512);
  k_reduce_parts<<<(P0C*DC)/256, 256, 0, stream>>>(partsX1, x1f, 16, P0C*DC);
  k_yS_part_b<<<dim3(P0C/64, 128), 256, 0, stream>>>(y, NC, S0h, P0C, partY1, NC, P0C, 64);
  k_yS_red<<<(TC*P0C + 255)/256, 256, 0, stream>>>(partY1, y1f, 128, TC*P0C);

  // ---- level 1 concatenated (split-K f32) ----
  k_gemm_nn_part<<<dim3(P0C/64, 4, 4), 256, 0, stream>>>(x1f, DC, Bcat, NCAT, partSA, P0C, NCAT, DC, 32);
  k_reduce_bias<<<(P0C*NCAT + 255)/256, 256, 0, stream>>>(partSA, biascat1, t1s1, 4, P0C, NCAT);
  k_gemm_nn_part<<<dim3(P0C/64, 4, 8), 256, 0, stream>>>(A1, P0C, t1s1, NCAT, partSB, P0C, NCAT, P0C, 64);
  k_reduce_stageB<<<(P0C*NCAT + P0C*8 + 255)/256, 256, 0, stream>>>(partSB, x1f, z1, s1agg, 8);

  k_rowscale<<<P0C, 256, 0, stream>>>(s1agg, P1C, rs1);
  k_smax_col<<<P1C, 256, 0, stream>>>(s1agg, rs1, S1, lossf, P0C, P1C);
  k_gemm_tn<<<dim3(P1C/64, DC/64, 16), 256, 0, stream>>>(S1, P1C, z1, DC, x2f, DC, P1C, DC, P0C, 32);
  k_yS_part<<<dim3(P1C/64, 8), 256, 0, stream>>>(y1f, P0C, S1, P1C, partY2, P0C, P1C, 64);
  k_yS_red<<<(TC*P1C + 255)/256, 256, 0, stream>>>(partY2, y2f, 8, TC*P1C);

  // ---- single fused emit ----
  k_emit_all<<<(out_size + 255)/256, 256, 0, stream>>>(x, x1f, x2f, y, y1f, y2f, lossf, out, out_size);
}

// Round 13
// 294.736 us; speedup vs baseline: 1.0761x; 1.0761x over previous
//
#include <hip/hip_runtime.h>
#include <hip/hip_bf16.h>

// Problem constants
#define NC   8192
#define EC   131072
#define DC   128
#define TC   8
#define P0C  512
#define P1C  128
#define ZIC  120
#define NCAT 248          // ZIC + P1C concatenated level-1 width
#define NW0  640          // P0C + DC concatenated level-0 width
#define TEMPC 200.0f
#define ATANH_MAX 6.1053405f  // atanh(f32(1-1e-5))

typedef short short8 __attribute__((ext_vector_type(8)));
typedef float f32x4 __attribute__((ext_vector_type(4)));

__device__ inline unsigned short f2b(float f) {  // f32 -> bf16 bits, RNE
  union { float f; unsigned u; } x; x.f = f;
  unsigned r = x.u + 0x7FFFu + ((x.u >> 16) & 1u);
  return (unsigned short)(r >> 16);
}
__device__ inline float b2f(unsigned short b) {
  union { unsigned u; float f; } x; x.u = ((unsigned)b) << 16; return x.f;
}

// ---------------------------------------------------------------------------
// One-shot prep: Wcat hi/lo ([640][128] B-operand = [Ws0 | We0_pad]),
// bias0cat[640] = bs0|be0, Bcat[128][248] = [We1_pad | Ws1], biascat1[248].
// ---------------------------------------------------------------------------
__global__ void k_prep(const float* __restrict__ Ws0, const float* __restrict__ We0,
                       const float* __restrict__ bs0, const float* __restrict__ be0,
                       const float* __restrict__ We1, const float* __restrict__ Ws1,
                       const float* __restrict__ be1, const float* __restrict__ bs1,
                       unsigned short* __restrict__ WcatHi, unsigned short* __restrict__ WcatLo,
                       float* __restrict__ bias0cat,
                       float* __restrict__ Bcat, float* __restrict__ biascat1)
{
  int idx = blockIdx.x * 256 + threadIdx.x;
  const int A = NW0 * DC;          // 81920
  const int B = A + NW0;           // +640
  const int Cc = B + DC * NCAT;    // +31744
  const int Dd = Cc + NCAT;        // +248
  if (idx < A) {
    int n = idx >> 7, k = idx & 127;
    float v;
    if (n < P0C) v = Ws0[(size_t)k * P0C + n];
    else {
      int nn = n - P0C;
      v = (nn < ZIC && k >= 8) ? We0[(size_t)(k - 8) * ZIC + nn] : 0.f;
    }
    unsigned short h = f2b(v);
    WcatHi[idx] = h; WcatLo[idx] = f2b(v - b2f(h));
  } else if (idx < B) {
    int n = idx - A;
    bias0cat[n] = (n < P0C) ? bs0[n] : ((n - P0C) < ZIC ? be0[n - P0C] : 0.f);
  } else if (idx < Cc) {
    int j = idx - B;
    int k = j / NCAT, n = j - k * NCAT;
    float v;
    if (n < ZIC) v = (k >= 8) ? We1[(size_t)(k - 8) * ZIC + n] : 0.f;
    else         v = Ws1[(size_t)k * P1C + (n - ZIC)];
    Bcat[j] = v;
  } else if (idx < Dd) {
    int n = idx - Cc;
    biascat1[n] = (n < ZIC) ? be1[n] : bs1[n - ZIC];
  }
}

// ---------------------------------------------------------------------------
// hi/lo-split bf16 MFMA, K=128 fixed, fused epilogue:
//   n < 512            -> sAgg[m*512+n] (f32) + row-sumsq atomics into rs_ss[m]
//   512 <= n < 632     -> zbufT[(n-512+8)*NC + m] (bf16, transposed, ushort4)
// ---------------------------------------------------------------------------
__global__ __launch_bounds__(256) void k_mfma_hilo2(
    const unsigned short* __restrict__ Ahi, const unsigned short* __restrict__ Alo,
    const unsigned short* __restrict__ Bhi, const unsigned short* __restrict__ Blo,
    const float* __restrict__ bias, const float* __restrict__ degf,
    float* __restrict__ C0, unsigned short* __restrict__ zT,
    float* __restrict__ rs_ss)
{
  __shared__ unsigned short Ah[64][136], Al[64][136], Bh[64][136], Bl[64][136];
  const int bm = blockIdx.x * 64, bn = blockIdx.y * 64;
  const int tid = threadIdx.x;
  const int lane = tid & 63, wave = tid >> 6;
  const int lrow = lane & 15, lgrp = lane >> 4;
#pragma unroll
  for (int p = 0; p < 4; ++p) {
    int id = p * 256 + tid;
    int r = id >> 4, c = id & 15;
    *(uint4*)(&Ah[r][c * 8]) = *(const uint4*)(Ahi + (size_t)(bm + r) * 128 + c * 8);
    *(uint4*)(&Al[r][c * 8]) = *(const uint4*)(Alo + (size_t)(bm + r) * 128 + c * 8);
    *(uint4*)(&Bh[r][c * 8]) = *(const uint4*)(Bhi + (size_t)(bn + r) * 128 + c * 8);
    *(uint4*)(&Bl[r][c * 8]) = *(const uint4*)(Blo + (size_t)(bn + r) * 128 + c * 8);
  }
  __syncthreads();
  f32x4 acc[4];
#pragma unroll
  for (int nt = 0; nt < 4; ++nt) acc[nt] = (f32x4){0.f, 0.f, 0.f, 0.f};
#pragma unroll
  for (int kk = 0; kk < 4; ++kk) {
    short8 ah = *(const short8*)(&Ah[wave * 16 + lrow][kk * 32 + lgrp * 8]);
    short8 al = *(const short8*)(&Al[wave * 16 + lrow][kk * 32 + lgrp * 8]);
#pragma unroll
    for (int nt = 0; nt < 4; ++nt) {
      short8 bh = *(const short8*)(&Bh[nt * 16 + lrow][kk * 32 + lgrp * 8]);
      short8 bl = *(const short8*)(&Bl[nt * 16 + lrow][kk * 32 + lgrp * 8]);
      acc[nt] = __builtin_amdgcn_mfma_f32_16x16x32_bf16(ah, bh, acc[nt], 0, 0, 0);
      acc[nt] = __builtin_amdgcn_mfma_f32_16x16x32_bf16(ah, bl, acc[nt], 0, 0, 0);
      acc[nt] = __builtin_amdgcn_mfma_f32_16x16x32_bf16(al, bh, acc[nt], 0, 0, 0);
    }
  }
  if (bn < P0C) {
    float pr[4] = {0.f, 0.f, 0.f, 0.f};
#pragma unroll
    for (int nt = 0; nt < 4; ++nt) {
      int n = bn + nt * 16 + lrow;
#pragma unroll
      for (int r = 0; r < 4; ++r) {
        int m = bm + wave * 16 + lgrp * 4 + r;
        float v = acc[nt][r] + degf[m] * bias[n];
        C0[(size_t)m * P0C + n] = v;
        pr[r] += v * v;
      }
    }
#pragma unroll
    for (int r = 0; r < 4; ++r) {
      float t = pr[r];
      t += __shfl_down(t, 8, 16);
      t += __shfl_down(t, 4, 16);
      t += __shfl_down(t, 2, 16);
      t += __shfl_down(t, 1, 16);
      if (lrow == 0) {
        int m = bm + wave * 16 + lgrp * 4 + r;
        atomicAdd(&rs_ss[m], t);
      }
    }
  } else {
#pragma unroll
    for (int nt = 0; nt < 4; ++nt) {
      int n = bn + nt * 16 + lrow;
      int col = n - P0C + 8;
      if (col >= DC) continue;
      int m0 = bm + wave * 16 + lgrp * 4;
      ushort4 pk;
      unsigned short* pp = (unsigned short*)&pk;
#pragma unroll
      for (int r = 0; r < 4; ++r) {
        int m = m0 + r;
        float v = acc[nt][r] + degf[m] * bias[n];
        pp[r] = f2b(v);
      }
      *(ushort4*)(zT + (size_t)col * NC + m0) = pk;
    }
  }
}

// rs[r] = TEMP * min(||row||, ATANH_MAX) / ||row|| from accumulated sumsq
__global__ void k_rs_final(const float* __restrict__ rs_ss, float* __restrict__ rs)
{
  int r = blockIdx.x * 256 + threadIdx.x;
  if (r >= NC) return;
  float n = sqrtf(rs_ss[r]);
  n = fmaxf(n, 1e-15f);
  rs[r] = TEMPC * fminf(n, ATANH_MAX) / n;
}

// ---------------------------------------------------------------------------
// f32 NN GEMM, split-K partials (level-1)
// ---------------------------------------------------------------------------
__global__ __launch_bounds__(256) void k_gemm_nn_part(
    const float* __restrict__ A, int lda,
    const float* __restrict__ B, int ldb,
    float* __restrict__ part,
    int M, int N, int K, int kchunk)
{
  __shared__ float As[16][65];
  __shared__ float Bs[16][65];
  int bm = blockIdx.x * 64, bn = blockIdx.y * 64;
  int z = blockIdx.z;
  int ks = z * kchunk, ke = min(K, ks + kchunk);
  int tid = threadIdx.x;
  int tm = (tid >> 4) << 2, tn = (tid & 15) << 2;
  float acc[4][4] = {};
  for (int k0 = ks; k0 < ke; k0 += 16) {
    for (int i = tid; i < 1024; i += 256) {
      int m = i >> 4, k = i & 15;
      float v = 0.f;
      if (bm + m < M && k0 + k < ke) v = A[(size_t)(bm + m) * lda + k0 + k];
      As[k][m] = v;
    }
    for (int i = tid; i < 1024; i += 256) {
      int k = i >> 6, n = i & 63;
      float v = 0.f;
      if (k0 + k < ke && bn + n < N) v = B[(size_t)(k0 + k) * ldb + bn + n];
      Bs[k][n] = v;
    }
    __syncthreads();
#pragma unroll
    for (int kk = 0; kk < 16; ++kk) {
      float a[4], b[4];
#pragma unroll
      for (int i = 0; i < 4; i++) a[i] = As[kk][tm + i];
#pragma unroll
      for (int j = 0; j < 4; j++) b[j] = Bs[kk][tn + j];
#pragma unroll
      for (int i = 0; i < 4; i++)
#pragma unroll
        for (int j = 0; j < 4; j++) acc[i][j] += a[i] * b[j];
    }
    __syncthreads();
  }
  size_t base = (size_t)z * M * N;
#pragma unroll
  for (int i = 0; i < 4; i++) {
    int m = bm + tm + i; if (m >= M) continue;
#pragma unroll
    for (int j = 0; j < 4; j++) {
      int n = bn + tn + j; if (n >= N) continue;
      part[base + (size_t)m * N + n] = acc[i][j];
    }
  }
}

__global__ void k_reduce_bias(const float* __restrict__ part,
                              const float* __restrict__ bias,
                              float* __restrict__ C, int nparts, int M, int N)
{
  int idx = blockIdx.x * 256 + threadIdx.x;
  if (idx >= M * N) return;
  int n = idx % N;
  float s = 0.f;
  for (int p = 0; p < nparts; ++p) s += part[(size_t)p * M * N + idx];
  if (bias) s += bias[n];
  C[idx] = s;
}

// stage-B reduce: split 512x248 partials into z1[:,8:128] and s1agg; tail copies z1[:, :8]
__global__ void k_reduce_stageB(const float* __restrict__ part,
                                const float* __restrict__ x1f,
                                float* __restrict__ z1, float* __restrict__ s1agg,
                                int nparts)
{
  int idx = blockIdx.x * 256 + threadIdx.x;
  const int MN = P0C * NCAT;
  if (idx < MN) {
    int m = idx / NCAT, n = idx - m * NCAT;
    float s = 0.f;
    for (int p = 0; p < nparts; ++p) s += part[(size_t)p * MN + idx];
    if (n < ZIC) z1[(size_t)m * DC + 8 + n] = s;
    else         s1agg[(size_t)m * P1C + (n - ZIC)] = s;
  } else if (idx < MN + P0C * 8) {
    int r = idx - MN; int m = r >> 3, c = r & 7;
    z1[(size_t)m * DC + c] = x1f[(size_t)m * DC + c];
  }
}

// ---------------------------------------------------------------------------
// Small f32 TN GEMM with split-K + atomics (x2 product)
// ---------------------------------------------------------------------------
__global__ __launch_bounds__(256) void k_gemm_tn(
    const float* __restrict__ A, int lda,
    const float* __restrict__ B, int ldb,
    float* __restrict__ C, int ldc,
    int M, int N, int K, int kchunk)
{
  __shared__ float As[16][65];
  __shared__ float Bs[16][65];
  int bm = blockIdx.x * 64, bn = blockIdx.y * 64;
  int ks = blockIdx.z * kchunk;
  int ke = min(K, ks + kchunk);
  int tid = threadIdx.x;
  int tm = (tid >> 4) << 2, tn = (tid & 15) << 2;
  float acc[4][4] = {};
  for (int k0 = ks; k0 < ke; k0 += 16) {
    for (int i = tid; i < 1024; i += 256) {
      int k = i >> 6, m = i & 63;
      float v = 0.f;
      if (k0 + k < ke && bm + m < M) v = A[(size_t)(k0 + k) * lda + bm + m];
      As[k][m] = v;
    }
    for (int i = tid; i < 1024; i += 256) {
      int k = i >> 6, n = i & 63;
      float v = 0.f;
      if (k0 + k < ke && bn + n < N) v = B[(size_t)(k0 + k) * ldb + bn + n];
      Bs[k][n] = v;
    }
    __syncthreads();
#pragma unroll
    for (int kk = 0; kk < 16; ++kk) {
      float a[4], b[4];
#pragma unroll
      for (int i = 0; i < 4; i++) a[i] = As[kk][tm + i];
#pragma unroll
      for (int j = 0; j < 4; j++) b[j] = Bs[kk][tn + j];
#pragma unroll
      for (int i = 0; i < 4; i++)
#pragma unroll
        for (int j = 0; j < 4; j++) acc[i][j] += a[i] * b[j];
    }
    __syncthreads();
  }
#pragma unroll
  for (int i = 0; i < 4; i++) {
    int m = bm + tm + i; if (m >= M) continue;
#pragma unroll
    for (int j = 0; j < 4; j++) {
      int n = bn + tn + j; if (n >= N) continue;
      atomicAdd(&C[(size_t)m * ldc + n], acc[i][j]);
    }
  }
}

// bf16 -> bf16 64x64 tile transpose
__global__ __launch_bounds__(256) void k_transpose_b2b(
    const unsigned short* __restrict__ src, int R, int C,
    unsigned short* __restrict__ dst)
{
  __shared__ unsigned short tile[64][65];
  int br = blockIdx.x * 64, bc = blockIdx.y * 64;
  for (int idx = threadIdx.x; idx < 4096; idx += 256) {
    int r = idx >> 6, c = idx & 63;
    tile[r][c] = src[(size_t)(br + r) * C + bc + c];
  }
  __syncthreads();
  for (int idx = threadIdx.x; idx < 4096; idx += 256) {
    int c = idx >> 6, r = idx & 63;
    dst[(size_t)(bc + c) * R + br + r] = tile[r][c];
  }
}

// ---------------------------------------------------------------------------
// bf16 MFMA NT GEMM: Cpart[z][M][N] = sum_k At[m][k]*Bt[n][k] over k-chunk z.
// ---------------------------------------------------------------------------
__global__ __launch_bounds__(256) void k_nt_bf16(
    const unsigned short* __restrict__ At,
    const unsigned short* __restrict__ Bt,
    float* __restrict__ Cpart,
    int M, int N, int K, int kchunk)
{
  __shared__ unsigned short Alds[64][136];
  __shared__ unsigned short Blds[64][136];
  const int bm = blockIdx.x * 64, bn = blockIdx.y * 64;
  const int z = blockIdx.z;
  const int k_beg = z * kchunk, k_end = k_beg + kchunk;
  const int tid = threadIdx.x;
  const int lane = tid & 63, wave = tid >> 6;
  const int lrow = lane & 15, lgrp = lane >> 4;
  f32x4 acc[4];
#pragma unroll
  for (int nt = 0; nt < 4; ++nt) acc[nt] = (f32x4){0.f, 0.f, 0.f, 0.f};

  for (int k0 = k_beg; k0 < k_end; k0 += 128) {
#pragma unroll
    for (int p = 0; p < 4; ++p) {
      int id = p * 256 + tid;
      int r = id >> 4;
      int c = id & 15;
      *(uint4*)(&Alds[r][c * 8]) =
          *(const uint4*)(At + (size_t)(bm + r) * K + k0 + c * 8);
      *(uint4*)(&Blds[r][c * 8]) =
          *(const uint4*)(Bt + (size_t)(bn + r) * K + k0 + c * 8);
    }
    __syncthreads();
#pragma unroll
    for (int kk = 0; kk < 4; ++kk) {
      short8 af = *(const short8*)(&Alds[wave * 16 + lrow][kk * 32 + lgrp * 8]);
#pragma unroll
      for (int nt = 0; nt < 4; ++nt) {
        short8 bf = *(const short8*)(&Blds[nt * 16 + lrow][kk * 32 + lgrp * 8]);
        acc[nt] = __builtin_amdgcn_mfma_f32_16x16x32_bf16(af, bf, acc[nt], 0, 0, 0);
      }
    }
    __syncthreads();
  }
  size_t base = (size_t)z * M * N;
#pragma unroll
  for (int nt = 0; nt < 4; ++nt) {
    int n = bn + nt * 16 + lrow;
#pragma unroll
    for (int r = 0; r < 4; ++r) {
      int m = bm + wave * 16 + lgrp * 4 + r;
      Cpart[base + (size_t)m * N + n] = acc[nt][r];
    }
  }
}

__global__ void k_reduce_parts(const float* __restrict__ part, float* __restrict__ C,
                               int nparts, int sz)
{
  int idx = blockIdx.x * 256 + threadIdx.x;
  if (idx >= sz) return;
  float s = 0.f;
  for (int p = 0; p < nparts; ++p) s += part[(size_t)p * sz + idx];
  C[idx] = s;
}

// ---------------------------------------------------------------------------
// CSR build (+degf folded into scan)
// ---------------------------------------------------------------------------
__global__ void k_count(const int* __restrict__ adj, int* __restrict__ counts)
{
  int e = blockIdx.x * 256 + threadIdx.x;
  if (e < EC) atomicAdd(&counts[adj[e]], 1);
}

__global__ __launch_bounds__(1024) void k_scan(const int* __restrict__ counts,
                                               int* __restrict__ offsets,
                                               float* __restrict__ degf)
{
  __shared__ int tsum[1024];
  int tid = threadIdx.x;
  int base = tid * 8;
  int loc[8]; int s = 0;
#pragma unroll
  for (int i = 0; i < 8; i++) { loc[i] = s; s += counts[base + i]; }
  tsum[tid] = s;
  __syncthreads();
  for (int off = 1; off < 1024; off <<= 1) {
    int v = (tid >= off) ? tsum[tid - off] : 0;
    __syncthreads();
    tsum[tid] += v;
    __syncthreads();
  }
  int excl = (tid == 0) ? 0 : tsum[tid - 1];
#pragma unroll
  for (int i = 0; i < 8; i++) {
    offsets[base + i] = excl + loc[i];
    degf[base + i] = (float)counts[base + i];
  }
  if (tid == 1023) offsets[NC] = tsum[1023];
}

__global__ void k_scatter(const int* __restrict__ adj, const int* __restrict__ offsets,
                          int* __restrict__ fill, int* __restrict__ csr)
{
  int e = blockIdx.x * 256 + threadIdx.x;
  if (e < EC) {
    int d = adj[e], s = adj[EC + e];
    int p = atomicAdd(&fill[d], 1);
    csr[offsets[d] + p] = s;
  }
}

// ---------------------------------------------------------------------------
// Aggregate raw x rows (multiplicity) -> hi/lo bf16 split of xa; also writes
// the 8 leading x-columns transposed into zbufT (bf16).
// ---------------------------------------------------------------------------
__global__ __launch_bounds__(128) void k_aggX(
    const int* __restrict__ offsets, const int* __restrict__ csr,
    const float* __restrict__ x,
    unsigned short* __restrict__ hi, unsigned short* __restrict__ lo,
    unsigned short* __restrict__ zT)
{
  int j = blockIdx.x;
  int beg = offsets[j], deg = offsets[j + 1] - beg;
  __shared__ int srcs[512];
  bool inl = (deg <= 512);
  if (inl) for (int i = threadIdx.x; i < deg; i += 128) srcs[i] = csr[beg + i];
  __syncthreads();
  int c = threadIdx.x;
  float acc = 0.f;
  if (inl) {
    int i = 0;
    for (; i + 4 <= deg; i += 4) {
      int s0 = srcs[i], s1 = srcs[i+1], s2 = srcs[i+2], s3 = srcs[i+3];
      float v0 = x[(size_t)s0 * DC + c], v1 = x[(size_t)s1 * DC + c];
      float v2 = x[(size_t)s2 * DC + c], v3 = x[(size_t)s3 * DC + c];
      acc += v0; acc += v1; acc += v2; acc += v3;
    }
    for (; i < deg; ++i) acc += x[(size_t)srcs[i] * DC + c];
  } else {
    for (int i = 0; i < deg; ++i) acc += x[(size_t)csr[beg + i] * DC + c];
  }
  unsigned short h = f2b(acc);
  hi[(size_t)j * DC + c] = h;
  lo[(size_t)j * DC + c] = f2b(acc - b2f(h));
  if (c < 8) zT[(size_t)c * NC + j] = f2b(x[(size_t)j * DC + c]);
}

// ---------------------------------------------------------------------------
// Mbh = bf16(A0_dedup @ S0): 256 threads, ushort2/lane, x8 ILP gather.
// (512-thread 1-col variant measured SLOWER: 2B/lane scalar loads, r12.)
// ---------------------------------------------------------------------------
__global__ __launch_bounds__(256) void k_aggM_bf16(
    const int* __restrict__ offsets, const int* __restrict__ csr,
    const unsigned short* __restrict__ S0h, unsigned short* __restrict__ Mbh)
{
  int j = blockIdx.x;
  int beg = offsets[j], deg = offsets[j + 1] - beg;
  __shared__ int srcs[512];
  __shared__ int nv_s;
  bool inl = (deg <= 512);
  if (inl) for (int i = threadIdx.x; i < deg; i += 256) srcs[i] = csr[beg + i];
  __syncthreads();
  if (inl) {
    for (int t = threadIdx.x; t < deg; t += 256) {
      int v = srcs[t];
      for (int u = 0; u < t; ++u)
        if (csr[beg + u] == v) { srcs[t] = -1; break; }
    }
  }
  __syncthreads();
  if (threadIdx.x == 0) {
    int nv = 0;
    if (inl) {
      for (int i = 0; i < deg; i++) if (srcs[i] >= 0) srcs[nv++] = srcs[i];
    }
    nv_s = nv;
  }
  __syncthreads();
  int c2 = threadIdx.x;
  float a0 = 0.f, a1 = 0.f;
  if (inl) {
    int nv = nv_s;
    int i = 0;
    for (; i + 8 <= nv; i += 8) {
      ushort2 v0 = *(const ushort2*)(S0h + (size_t)srcs[i]   * P0C + c2 * 2);
      ushort2 v1 = *(const ushort2*)(S0h + (size_t)srcs[i+1] * P0C + c2 * 2);
      ushort2 v2 = *(const ushort2*)(S0h + (size_t)srcs[i+2] * P0C + c2 * 2);
      ushort2 v3 = *(const ushort2*)(S0h + (size_t)srcs[i+3] * P0C + c2 * 2);
      ushort2 v4 = *(const ushort2*)(S0h + (size_t)srcs[i+4] * P0C + c2 * 2);
      ushort2 v5 = *(const ushort2*)(S0h + (size_t)srcs[i+5] * P0C + c2 * 2);
      ushort2 v6 = *(const ushort2*)(S0h + (size_t)srcs[i+6] * P0C + c2 * 2);
      ushort2 v7 = *(const ushort2*)(S0h + (size_t)srcs[i+7] * P0C + c2 * 2);
      a0 += b2f(v0.x) + b2f(v1.x) + b2f(v2.x) + b2f(v3.x)
          + b2f(v4.x) + b2f(v5.x) + b2f(v6.x) + b2f(v7.x);
      a1 += b2f(v0.y) + b2f(v1.y) + b2f(v2.y) + b2f(v3.y)
          + b2f(v4.y) + b2f(v5.y) + b2f(v6.y) + b2f(v7.y);
    }
    for (; i < nv; ++i) {
      ushort2 v = *(const ushort2*)(S0h + (size_t)srcs[i] * P0C + c2 * 2);
      a0 += b2f(v.x); a1 += b2f(v.y);
    }
  } else {
    for (int i = 0; i < deg; i++) {
      int s = csr[beg + i];
      bool dup = false;
      for (int u = 0; u < i; u++) if (csr[beg + u] == s) { dup = true; break; }
      if (!dup) {
        ushort2 v = *(const ushort2*)(S0h + (size_t)s * P0C + c2 * 2);
        a0 += b2f(v.x); a1 += b2f(v.y);
      }
    }
  }
  ushort2 o2; o2.x = f2b(a0); o2.y = f2b(a1);
  *(ushort2*)(Mbh + (size_t)j * P0C + c2 * 2) = o2;
}

// ---------------------------------------------------------------------------
// Column softmax (axis=0) over 8192 rows, two-stage online
// ---------------------------------------------------------------------------
__global__ __launch_bounds__(256) void k_smaxA(const float* __restrict__ U,
    const float* __restrict__ rs, float* __restrict__ pm, float* __restrict__ ps,
    int rows, int cols, int rpg)
{
  int lc = threadIdx.x & 63;
  int c = blockIdx.x * 64 + lc;
  int rl = threadIdx.x >> 6;
  int r0 = blockIdx.y * rpg, r1 = min(rows, r0 + rpg);
  float m = -1e30f, s = 0.f;
  for (int r = r0 + rl; r < r1; r += 4) {
    float l = rs[r] * U[(size_t)r * cols + c];
    if (l > m) { s = s * __expf(m - l) + 1.f; m = l; }
    else s += __expf(l - m);
  }
  __shared__ float sm[4][64], sv[4][64];
  sm[rl][lc] = m; sv[rl][lc] = s;
  __syncthreads();
  if (threadIdx.x < 64) {
    float mm = sm[0][threadIdx.x], s2 = sv[0][threadIdx.x];
    for (int q = 1; q < 4; q++) {
      float mq = sm[q][threadIdx.x], sq = sv[q][threadIdx.x];
      float mn = fmaxf(mm, mq);
      s2 = s2 * __expf(mm - mn) + sq * __expf(mq - mn);
      mm = mn;
    }
    pm[(size_t)blockIdx.y * cols + blockIdx.x * 64 + threadIdx.x] = mm;
    ps[(size_t)blockIdx.y * cols + blockIdx.x * 64 + threadIdx.x] = s2;
  }
}

__global__ void k_smaxB(const float* __restrict__ pm, const float* __restrict__ ps,
                        float* __restrict__ colm, float* __restrict__ colsum,
                        int ng, int cols)
{
  int c = blockIdx.x * blockDim.x + threadIdx.x;
  if (c >= cols) return;
  float m = -1e30f, s = 0.f;
  for (int g = 0; g < ng; g++) {
    float mg = pm[(size_t)g * cols + c], sg = ps[(size_t)g * cols + c];
    float mn = fmaxf(m, mg);
    s = s * __expf(m - mn) + sg * __expf(mg - mn);
    m = mn;
  }
  colm[c] = m; colsum[c] = s;
}

// Final softmax pass: writes row-major bf16 Sh AND transposed bf16 ST, + entropy.
__global__ __launch_bounds__(256) void k_smaxC(const float* __restrict__ U,
    const float* __restrict__ rs, const float* __restrict__ colm,
    const float* __restrict__ colsum,
    unsigned short* __restrict__ Sh, unsigned short* __restrict__ ST,
    float* __restrict__ loss, int rows, int cols)
{
  __shared__ unsigned short tile[64][258];
  __shared__ float red[4];
  int lc = threadIdx.x & 63;
  int gc = blockIdx.x * 64 + lc;
  int rl = threadIdx.x >> 6;
  int r0 = blockIdx.y * 256;
  float m = colm[gc], inv = 1.f / colsum[gc];
  float h = 0.f;
  for (int rr = rl; rr < 256; rr += 4) {
    int r = r0 + rr;
    float l = rs[r] * U[(size_t)r * cols + gc];
    float p = __expf(l - m) * inv;
    unsigned short pb = f2b(p);
    Sh[(size_t)r * cols + gc] = pb;
    tile[lc][rr] = pb;
    if (p > 0.f) h -= p * __logf(p);
  }
  for (int off = 32; off > 0; off >>= 1) h += __shfl_down(h, off);
  if ((threadIdx.x & 63) == 0) red[threadIdx.x >> 6] = h;
  __syncthreads();
  if (threadIdx.x == 0) atomicAdd(loss, red[0] + red[1] + red[2] + red[3]);
  int gc0 = blockIdx.x * 64;
  for (int idx = threadIdx.x; idx < 64 * 256; idx += 256) {
    int col = idx >> 8, rr = idx & 255;
    ST[(size_t)(gc0 + col) * rows + r0 + rr] = tile[col][rr];
  }
}

// ---------------------------------------------------------------------------
// Level-1: row scale (small) + column softmax
// ---------------------------------------------------------------------------
__global__ __launch_bounds__(256) void k_rowscale(const float* __restrict__ U, int cols,
                                                  float* __restrict__ rs)
{
  int r = blockIdx.x;
  const float* row = U + (size_t)r * cols;
  float ss = 0.f;
  for (int c = threadIdx.x; c < cols; c += 256) { float v = row[c]; ss += v * v; }
  for (int off = 32; off > 0; off >>= 1) ss += __shfl_down(ss, off);
  __shared__ float red[4];
  if ((threadIdx.x & 63) == 0) red[threadIdx.x >> 6] = ss;
  __syncthreads();
  if (threadIdx.x == 0) {
    float n = sqrtf(red[0] + red[1] + red[2] + red[3]);
    n = fmaxf(n, 1e-15f);
    rs[r] = TEMPC * fminf(n, ATANH_MAX) / n;
  }
}

__global__ __launch_bounds__(256) void k_smax_col(const float* __restrict__ U,
    const float* __restrict__ rs, float* __restrict__ S, float* __restrict__ loss,
    int rows, int cols)
{
  int c = blockIdx.x;
  int tid = threadIdx.x;
  int r0 = tid, r1 = tid + 256;
  float v0 = rs[r0] * U[(size_t)r0 * cols + c];
  float v1 = rs[r1] * U[(size_t)r1 * cols + c];
  float m = fmaxf(v0, v1);
  for (int off = 32; off > 0; off >>= 1) m = fmaxf(m, __shfl_xor(m, off));
  __shared__ float red[4];
  if ((tid & 63) == 0) red[tid >> 6] = m;
  __syncthreads();
  m = fmaxf(fmaxf(red[0], red[1]), fmaxf(red[2], red[3]));
  float e0 = __expf(v0 - m), e1 = __expf(v1 - m);
  float s = e0 + e1;
  for (int off = 32; off > 0; off >>= 1) s += __shfl_xor(s, off);
  __syncthreads();
  __shared__ float red2[4];
  if ((tid & 63) == 0) red2[tid >> 6] = s;
  __syncthreads();
  s = red2[0] + red2[1] + red2[2] + red2[3];
  float inv = 1.f / s;
  float p0 = e0 * inv, p1 = e1 * inv;
  S[(size_t)r0 * cols + c] = p0;
  S[(size_t)r1 * cols + c] = p1;
  float h = 0.f;
  if (p0 > 0.f) h -= p0 * __logf(p0);
  if (p1 > 0.f) h -= p1 * __logf(p1);
  for (int off = 32; off > 0; off >>= 1) h += __shfl_xor(h, off);
  __syncthreads();
  __shared__ float red3[4];
  if ((tid & 63) == 0) red3[tid >> 6] = h;
  __syncthreads();
  if (tid == 0) atomicAdd(loss, red3[0] + red3[1] + red3[2] + red3[3]);
}

// ---------------------------------------------------------------------------
// y-projection via split-K partials (f32 S variant and bf16 S variant)
// ---------------------------------------------------------------------------
__global__ __launch_bounds__(256) void k_yS_part(
    const float* __restrict__ Y, int ldy,
    const float* __restrict__ S, int ldS,
    float* __restrict__ part, int K, int C, int kchunk)
{
  int lc = threadIdx.x & 63;
  int c = blockIdx.x * 64 + lc;
  int rl = threadIdx.x >> 6;
  int r0 = blockIdx.y * kchunk, r1 = min(K, r0 + kchunk);
  float acc[8] = {};
  for (int r = r0 + rl; r < r1; r += 4) {
    float sv = S[(size_t)r * ldS + c];
#pragma unroll
    for (int t = 0; t < 8; t++) acc[t] += Y[(size_t)t * ldy + r] * sv;
  }
  __shared__ float red[4][8][64];
#pragma unroll
  for (int t = 0; t < 8; t++) red[rl][t][lc] = acc[t];
  __syncthreads();
  if (rl == 0) {
#pragma unroll
    for (int t = 0; t < 8; t++) {
      float v = red[0][t][lc] + red[1][t][lc] + red[2][t][lc] + red[3][t][lc];
      part[((size_t)blockIdx.y * 8 + t) * C + c] = v;
    }
  }
}

__global__ __launch_bounds__(256) void k_yS_part_b(
    const float* __restrict__ Y, int ldy,
    const unsigned short* __restrict__ S, int ldS,
    float* __restrict__ part, int K, int C, int kchunk)
{
  int lc = threadIdx.x & 63;
  int c = blockIdx.x * 64 + lc;
  int rl = threadIdx.x >> 6;
  int r0 = blockIdx.y * kchunk, r1 = min(K, r0 + kchunk);
  float acc[8] = {};
  for (int r = r0 + rl; r < r1; r += 4) {
    float sv = b2f(S[(size_t)r * ldS + c]);
#pragma unroll
    for (int t = 0; t < 8; t++) acc[t] += Y[(size_t)t * ldy + r] * sv;
  }
  __shared__ float red[4][8][64];
#pragma unroll
  for (int t = 0; t < 8; t++) red[rl][t][lc] = acc[t];
  __syncthreads();
  if (rl == 0) {
#pragma unroll
    for (int t = 0; t < 8; t++) {
      float v = red[0][t][lc] + red[1][t][lc] + red[2][t][lc] + red[3][t][lc];
      part[((size_t)blockIdx.y * 8 + t) * C + c] = v;
    }
  }
}

__global__ void k_yS_red(const float* __restrict__ part, float* __restrict__ outp,
                         int nparts, int sz)
{
  int idx = blockIdx.x * 256 + threadIdx.x;
  if (idx >= sz) return;
  float s = 0.f;
  for (int p = 0; p < nparts; ++p) s += part[(size_t)p * sz + idx];
  outp[idx] = s;
}

// ---------------------------------------------------------------------------
// Single fused output emit (all regions of d_out)
// ---------------------------------------------------------------------------
__global__ void k_emit_all(const float* __restrict__ x, const float* __restrict__ x1f,
                           const float* __restrict__ x2f, const float* __restrict__ y,
                           const float* __restrict__ y1f, const float* __restrict__ y2f,
                           const float* __restrict__ lossf, float* __restrict__ out,
                           int total)
{
  int idx = blockIdx.x * 256 + threadIdx.x;
  if (idx >= total) return;
  float v;
  if (idx < 1048576) v = x[idx];                       // NC*DC
  else if (idx < 1114112) v = x1f[idx - 1048576];      // +P0C*DC
  else if (idx < 1130496) v = x2f[idx - 1114112];      // +P1C*DC
  else if (idx < 1201152) {                            // y region, YW=8832
    int r = idx - 1130496;
    int t = r / 8832, c = r - t * 8832;
    if (c < 8192) v = y[(size_t)t * 8192 + c];
    else if (c < 8704) v = y1f[t * 512 + (c - 8192)];
    else v = y2f[t * 128 + (c - 8704)];
  } else v = lossf[0];
  out[idx] = v;
}

// ---------------------------------------------------------------------------
extern "C" void kernel_launch(void* const* d_in, const int* in_sizes, int n_in,
                              void* d_out, int out_size, void* d_ws, size_t ws_size,
                              hipStream_t stream)
{
  (void)in_sizes; (void)n_in; (void)ws_size;
  const float* x   = (const float*)d_in[0];
  const float* y   = (const float*)d_in[1];
  const float* We0 = (const float*)d_in[2];
  const float* be0 = (const float*)d_in[3];
  const float* Ws0 = (const float*)d_in[4];
  const float* bs0 = (const float*)d_in[5];
  const float* We1 = (const float*)d_in[6];
  const float* be1 = (const float*)d_in[7];
  const float* Ws1 = (const float*)d_in[8];
  const float* bs1 = (const float*)d_in[9];
  const int*   adj = (const int*)d_in[10];
  float* out = (float*)d_out;

  float* ws = (float*)d_ws;
  size_t o = 0;
  auto alloc = [&](size_t n) { float* p = ws + o; o += n; return p; };
  float* sAgg  = alloc((size_t)NC * P0C);    // logits; then Mbh(bf16) + A1 partials
  float* zbuf  = alloc((size_t)NC * DC);     // x1 partials only
  float* rsc   = alloc(NC);
  float* degf  = alloc(NC);
  float* pm    = alloc(32 * P0C);
  float* ps    = alloc(32 * P0C);
  float* colm  = alloc(P0C);
  float* colsum= alloc(P0C);
  float* s1agg = alloc((size_t)P0C * P1C);
  float* S1    = alloc((size_t)P0C * P1C);
  float* z1    = alloc((size_t)P0C * P1C);
  float* rs1   = alloc(P0C);
  float* x1f   = alloc((size_t)P0C * DC);
  float* A1    = alloc((size_t)P0C * P0C);
  unsigned short* S0T   = (unsigned short*)alloc((size_t)P0C * NC / 2);
  unsigned short* MbT   = (unsigned short*)alloc((size_t)P0C * NC / 2);
  unsigned short* zbufT = (unsigned short*)alloc((size_t)DC * NC / 2);
  unsigned short* S0h   = (unsigned short*)alloc((size_t)NC * P0C / 2);
  unsigned short* xaHi  = (unsigned short*)alloc((size_t)NC * DC / 2);
  unsigned short* xaLo  = (unsigned short*)alloc((size_t)NC * DC / 2);
  unsigned short* WcatHi= (unsigned short*)alloc((size_t)NW0 * DC / 2);
  unsigned short* WcatLo= (unsigned short*)alloc((size_t)NW0 * DC / 2);
  float* bias0cat = alloc(NW0);
  float* Bcat   = alloc((size_t)DC * NCAT);
  float* biascat1= alloc(NCAT);
  float* t1s1   = alloc((size_t)P0C * NCAT);
  float* partSA = alloc((size_t)4 * P0C * NCAT);
  float* partSB = alloc((size_t)8 * P0C * NCAT);
  float* partY1 = alloc((size_t)128 * TC * P0C);
  float* partY2 = alloc((size_t)8 * TC * P1C);
  // atomic-accumulated zone (contiguous, zeroed every call)
  float* rs_ss = alloc(NC);
  float* x2f   = alloc((size_t)P1C * DC);
  float* y1f   = alloc((size_t)TC * P0C);
  float* y2f   = alloc((size_t)TC * P1C);
  float* lossf = alloc(1);
  size_t atomicFloats = (size_t)NC + (size_t)P1C*DC + (size_t)TC*P0C + (size_t)TC*P1C + 1;
  o = (o + 63) & ~(size_t)63;
  int* ibase   = (int*)(ws + o);
  int* counts  = ibase;
  int* fill    = ibase + NC;
  int* offsets = ibase + 2 * NC;
  int* csr     = ibase + 2 * NC + (NC + 1);

  unsigned short* Mbh = (unsigned short*)sAgg;          // bf16 8192x512 (8 MB)
  float* partsA1 = sAgg + (size_t)2 * 1024 * 1024;      // 8x512x512 f32 (8 MB)
  float* partsX1 = zbuf;                                // 16x512x128 f32

  hipMemsetAsync(rs_ss, 0, atomicFloats * sizeof(float), stream);
  hipMemsetAsync(counts, 0, 2 * NC * sizeof(int), stream);

  // ---- CSR build + degree + weight preps ----
  k_count  <<<EC/256, 256, 0, stream>>>(adj, counts);
  k_scan   <<<1, 1024, 0, stream>>>(counts, offsets, degf);
  k_scatter<<<EC/256, 256, 0, stream>>>(adj, offsets, fill, csr);
  k_prep<<<(NW0*DC + NW0 + DC*NCAT + NCAT + 255)/256, 256, 0, stream>>>(
      Ws0, We0, bs0, be0, We1, Ws1, be1, bs1,
      WcatHi, WcatLo, bias0cat, Bcat, biascat1);

  // ---- aggregate raw x (hi/lo direct), fused MFMA: sAgg + zbufT + rs_ss ----
  k_aggX<<<NC, 128, 0, stream>>>(offsets, csr, x, xaHi, xaLo, zbufT);
  k_mfma_hilo2<<<dim3(NC/64, NW0/64), 256, 0, stream>>>(xaHi, xaLo, WcatHi, WcatLo,
                                                        bias0cat, degf, sAgg, zbufT, rs_ss);
  k_rs_final<<<NC/256, 256, 0, stream>>>(rs_ss, rsc);

  // ---- column softmax -> S0h + S0T, entropy ----
  k_smaxA<<<dim3(P0C/64, 32), 256, 0, stream>>>(sAgg, rsc, pm, ps, NC, P0C, 256);
  k_smaxB<<<P0C/256, 256, 0, stream>>>(pm, ps, colm, colsum, 32, P0C);
  k_smaxC<<<dim3(P0C/64, 32), 256, 0, stream>>>(sAgg, rsc, colm, colsum, S0h, S0T, lossf, NC, P0C);

  // ---- Mbh = bf16(A0_dedup @ S0) ; transpose ----
  k_aggM_bf16<<<NC, 256, 0, stream>>>(offsets, csr, S0h, Mbh);
  k_transpose_b2b<<<dim3(NC/64, P0C/64), 256, 0, stream>>>(Mbh, NC, P0C, MbT);

  // ---- pooled products via bf16 MFMA (split-K partials + reduce) ----
  k_nt_bf16<<<dim3(P0C/64, P0C/64, 8), 256, 0, stream>>>(S0T, MbT, partsA1, P0C, P0C, NC, 1024);
  k_reduce_parts<<<(P0C*P0C)/256, 256, 0, stream>>>(partsA1, A1, 8, P0C*P0C);
  k_nt_bf16<<<dim3(P0C/64, DC/64, 16), 256, 0, stream>>>(S0T, zbufT, partsX1, P0C, DC, NC, 512);
  k_reduce_parts<<<(P0C*DC)/256, 256, 0, stream>>>(partsX1, x1f, 16, P0C*DC);
  k_yS_part_b<<<dim3(P0C/64, 128), 256, 0, stream>>>(y, NC, S0h, P0C, partY1, NC, P0C, 64);
  k_yS_red<<<(TC*P0C + 255)/256, 256, 0, stream>>>(partY1, y1f, 128, TC*P0C);

  // ---- level 1 concatenated (split-K f32) ----
  k_gemm_nn_part<<<dim3(P0C/64, 4, 4), 256, 0, stream>>>(x1f, DC, Bcat, NCAT, partSA, P0C, NCAT, DC, 32);
  k_reduce_bias<<<(P0C*NCAT + 255)/256, 256, 0, stream>>>(partSA, biascat1, t1s1, 4, P0C, NCAT);
  k_gemm_nn_part<<<dim3(P0C/64, 4, 8), 256, 0, stream>>>(A1, P0C, t1s1, NCAT, partSB, P0C, NCAT, P0C, 64);
  k_reduce_stageB<<<(P0C*NCAT + P0C*8 + 255)/256, 256, 0, stream>>>(partSB, x1f, z1, s1agg, 8);

  k_rowscale<<<P0C, 256, 0, stream>>>(s1agg, P1C, rs1);
  k_smax_col<<<P1C, 256, 0, stream>>>(s1agg, rs1, S1, lossf, P0C, P1C);
  k_gemm_tn<<<dim3(P1C/64, DC/64, 16), 256, 0, stream>>>(S1, P1C, z1, DC, x2f, DC, P1C, DC, P0C, 32);
  k_yS_part<<<dim3(P1C/64, 8), 256, 0, stream>>>(y1f, P0C, S1, P1C, partY2, P0C, P1C, 64);
  k_yS_red<<<(TC*P1C + 255)/256, 256, 0, stream>>>(partY2, y2f, 8, TC*P1C);

  // ---- single fused emit ----
  k_emit_all<<<(out_size + 255)/256, 256, 0, stream>>>(x, x1f, x2f, y, y1f, y2f, lossf, out, out_size);
}